// Round 2
// baseline (1185.572 us; speedup 1.0000x reference)
//
#include <hip/hip_runtime.h>
#include <math.h>

#define EPSF 1e-6f

#define NL 4
#define NB 8
#define NE 1024
#define NH 16
#define ND 64
#define NG 4096
#define NIMG 256
#define NTT 64
#define NV 16385

// ---- workspace float offsets ----
// atomic (zeroed each call) region:
#define AX    0          // x[1..4], 4*8192
#define AQS   32768      // q_self[4][8192]
#define AKV   65536      // kv[4][16*1024]
#define ASS   131072     // s_self[4][8192]
#define AQE   163840     // q_enc[4][8192]
#define AOE   196608     // o_enc[4][8192]
#define ASE   229376     // s_enc[4][8192]
#define AGA   262144     // gA[4][32768]
#define AGB   393216     // gB[4][32768]
#define AEND  524288
// direct-write region:
#define DX0   524288
#define DAT   532480
#define DX2   540672
#define DX3   548864
#define DQW   557056
#define DWX   688128
#define DG    819200

__device__ inline void wave_red2(float& a, float& b) {
#pragma unroll
  for (int o = 32; o; o >>= 1) { a += __shfl_xor(a, o); b += __shfl_xor(b, o); }
}

// ---------------- generic matvec: out[m][8][N] (+=) = h[8][BK-slice] @ W[m] ----------------
struct MvP {
  const float* W0; const float* W1; const float* W2;
  float* out0; float* out1; float* out2;
  const float* xin;    // base input rows [8][K]
  const float* sres;   // mode2: s input for inner LN
  const float* lnb1; const float* lns1;  // mode2 inner LN params
  const float* lnb2; const float* lns2;  // outer LN params (mode1/2/3)
  float* x2store;      // mode2: block 0 stores composed x2
  const float* resid;  // epilogue: added once (ks==0)
  int K, N, CB, KS, nmat, mode;  // mode: 0 copy, 1 LN(xin), 2 x2=xin+LN(sres);h=LN(x2), 3 LN width K
};

__global__ __launch_bounds__(256) void mv_kernel(MvP p) {
  __shared__ float xf[8 * 1024];
  __shared__ float h[8 * 256];
  const int tid = threadIdx.x, wv = tid >> 6, ln = tid & 63;
  const int per = p.CB * p.KS;
  const int m = blockIdx.x / per, rem = blockIdx.x % per;
  const int ks = rem / p.CB, cb = rem % p.CB;
  const int BK = p.K / p.KS;
  const int k0 = ks * BK, n0 = cb * 256;

  if (p.mode == 0) {
    for (int i = tid; i < 8 * BK; i += 256) {
      int r = i / BK, kk = i % BK;
      h[r * BK + kk] = p.xin[r * p.K + k0 + kk];
    }
  } else if (p.mode == 1 || p.mode == 3) {
    for (int r = wv; r < 8; r += 4) {
      float s = 0.f, ss = 0.f;
      for (int i = ln; i < p.K; i += 64) { float v = p.xin[r * p.K + i]; s += v; ss += v * v; }
      wave_red2(s, ss);
      float mean = s / p.K, var = ss / p.K - mean * mean, rs = rsqrtf(var + EPSF);
      for (int i = k0 + ln; i < k0 + BK; i += 64) {
        float sc = p.lns2 ? p.lns2[i] : 1.f;
        h[r * BK + (i - k0)] = (p.xin[r * p.K + i] - mean) * rs * sc + p.lnb2[i];
      }
    }
  } else {  // mode 2
    for (int r = wv; r < 8; r += 4) {
      float s = 0.f, ss = 0.f;
      for (int i = ln; i < 1024; i += 64) { float v = p.sres[r * 1024 + i]; s += v; ss += v * v; }
      wave_red2(s, ss);
      float mean = s / 1024.f, var = ss / 1024.f - mean * mean, rs = rsqrtf(var + EPSF);
      float s2 = 0.f, ss2 = 0.f;
      for (int i = ln; i < 1024; i += 64) {
        float sc = p.lns1 ? p.lns1[i] : 1.f;
        float v = p.xin[r * 1024 + i] + (p.sres[r * 1024 + i] - mean) * rs * sc + p.lnb1[i];
        xf[r * 1024 + i] = v; s2 += v; ss2 += v * v;
      }
      wave_red2(s2, ss2);
      float m2 = s2 / 1024.f, v2 = ss2 / 1024.f - m2 * m2, rs2 = rsqrtf(v2 + EPSF);
      for (int i = k0 + ln; i < k0 + BK; i += 64)
        h[r * BK + (i - k0)] = (xf[r * 1024 + i] - m2) * rs2 + p.lnb2[i];
      if (p.x2store && blockIdx.x == 0)
        for (int i = ln; i < 1024; i += 64) p.x2store[r * 1024 + i] = xf[r * 1024 + i];
    }
  }
  __syncthreads();

  const int col = n0 + tid;
  if (col >= p.N) return;
  const float* W = (m == 0) ? p.W0 : (m == 1) ? p.W1 : p.W2;
  float* out = (m == 0) ? p.out0 : (m == 1) ? p.out1 : p.out2;
  float acc[8] = {0.f, 0.f, 0.f, 0.f, 0.f, 0.f, 0.f, 0.f};
  const float* wp = W + (size_t)k0 * p.N + col;
#pragma unroll 4
  for (int kk = 0; kk < BK; ++kk) {
    float w = wp[(size_t)kk * p.N];
#pragma unroll
    for (int r = 0; r < 8; ++r) acc[r] += h[r * BK + kk] * w;
  }
#pragma unroll
  for (int r = 0; r < 8; ++r) {
    float add = acc[r];
    if (p.resid && ks == 0) add += p.resid[r * p.N + col];
    atomicAdd(&out[(size_t)r * p.N + col], add);
  }
}

// ---------------- ast passthrough copy ----------------
__global__ void copy_ast(const float4* __restrict__ in, float4* __restrict__ out, int n4) {
  int i = blockIdx.x * blockDim.x + threadIdx.x;
  int st = gridDim.x * blockDim.x;
  for (; i < n4; i += st) out[i] = in[i];
}

// ---------------- embedding + LN ----------------
__global__ __launch_bounds__(256) void embed_kernel(const float* __restrict__ tok,
    const float* __restrict__ pos, const int* __restrict__ prev, const int* __restrict__ tixp,
    const float* __restrict__ lnb, const float* __restrict__ lns, float* __restrict__ x0) {
  int b = blockIdx.x;
  const float* te = tok + (size_t)prev[0] * NE;
  const float* pe = pos + (size_t)tixp[0] * NE;
  __shared__ float row[NE];
  __shared__ float aa[4], bb[4];
  int tid = threadIdx.x;
  float s = 0.f, ss = 0.f;
  for (int i = tid; i < NE; i += 256) { float v = te[i] + pe[i]; row[i] = v; s += v; ss += v * v; }
  wave_red2(s, ss);
  if ((tid & 63) == 0) { aa[tid >> 6] = s; bb[tid >> 6] = ss; }
  __syncthreads();
  s = aa[0] + aa[1] + aa[2] + aa[3]; ss = bb[0] + bb[1] + bb[2] + bb[3];
  float m = s / NE, var = ss / NE - m * m, rs = rsqrtf(var + EPSF);
  for (int i = tid; i < NE; i += 256) x0[(size_t)b * NE + i] = (row[i] - m) * rs * lns[i] + lnb[i];
}

// ---------------- self attention core ----------------
__global__ __launch_bounds__(256) void self_attn_kernel(const float* __restrict__ q_self,
    const float* __restrict__ kvf, const float* __restrict__ ast, const int* __restrict__ tixp,
    float* __restrict__ attnout) {
  int b = blockIdx.x >> 4, hh = blockIdx.x & 15;
  int tid = threadIdx.x;
  int tix = tixp[0];
  int T = tix + 1; if (T > NIMG) T = NIMG;
  __shared__ float qv[64];
  __shared__ float sc[256];
  __shared__ float red[256];
  if (tid < 64) qv[tid] = q_self[(size_t)b * NE + hh * 64 + tid] * 0.125f;
  __syncthreads();
  float sj = -INFINITY;
  if (tid < T) {
    const float* kr = (tid == tix) ? (kvf + (size_t)b * NE + hh * 64)
                                   : (ast + ((size_t)b * NIMG + tid) * NE + hh * 64);
    float s = 0.f;
#pragma unroll
    for (int d0 = 0; d0 < 64; d0 += 4) {
      float4 k4 = *reinterpret_cast<const float4*>(kr + d0);
      s += qv[d0] * k4.x + qv[d0 + 1] * k4.y + qv[d0 + 2] * k4.z + qv[d0 + 3] * k4.w;
    }
    sj = s;
  }
  red[tid] = sj; __syncthreads();
  for (int o = 128; o; o >>= 1) { if (tid < o) red[tid] = fmaxf(red[tid], red[tid + o]); __syncthreads(); }
  float mx = red[0]; __syncthreads();
  float e = (tid < T) ? __expf(sj - mx) : 0.f;
  red[tid] = e; __syncthreads();
  for (int o = 128; o; o >>= 1) { if (tid < o) red[tid] += red[tid + o]; __syncthreads(); }
  float inv = 1.f / red[0];
  sc[tid] = e * inv;
  __syncthreads();
  int d = tid & 63, jc = tid >> 6;
  float part = 0.f;
  for (int j = jc; j < T; j += 4) {
    const float* vr = (j == tix) ? (kvf + (size_t)(8 + b) * NE + hh * 64)
                                 : (ast + ((size_t)(8 + b) * NIMG + j) * NE + hh * 64);
    part += sc[j] * vr[d];
  }
  red[tid] = part; __syncthreads();
  if (tid < 64)
    attnout[(size_t)b * NE + hh * 64 + tid] = red[tid] + red[tid + 64] + red[tid + 128] + red[tid + 192];
}

// ---------------- qW[b,h,e] = sum_d q_enc[b,h*64+d] * Wk[e,h*64+d] ----------------
__global__ __launch_bounds__(256) void qw_kernel(const float* __restrict__ q_enc,
    const float* __restrict__ Wk, float* __restrict__ qW) {
  int hh = blockIdx.x >> 2, ec = blockIdx.x & 3;
  int tid = threadIdx.x;
  int e = ec * 256 + tid;
  __shared__ float ql[8][64];
  for (int i = tid; i < 512; i += 256) { int r = i >> 6, d = i & 63; ql[r][d] = q_enc[(size_t)r * NE + hh * 64 + d]; }
  __syncthreads();
  const float* wrow = Wk + (size_t)e * NE + hh * 64;
  float acc[8] = {0.f, 0.f, 0.f, 0.f, 0.f, 0.f, 0.f, 0.f};
#pragma unroll
  for (int d0 = 0; d0 < 64; d0 += 4) {
    float4 w4 = *reinterpret_cast<const float4*>(wrow + d0);
#pragma unroll
    for (int r = 0; r < 8; ++r)
      acc[r] += ql[r][d0] * w4.x + ql[r][d0 + 1] * w4.y + ql[r][d0 + 2] * w4.z + ql[r][d0 + 3] * w4.w;
  }
#pragma unroll
  for (int r = 0; r < 8; ++r) qW[(size_t)(r * NH + hh) * NE + e] = acc[r];
}

// ---------------- cross attention core: scores = qW.X^T/8, softmax, wX = w.X ----------------
// mask buffer may be uint8 bools (1 byte each) or int32 (4 bytes each); detect on device.
__global__ __launch_bounds__(256) void cross_attn_kernel(const float* __restrict__ qW,
    const float* __restrict__ X, const void* __restrict__ maskp, float* __restrict__ wX) {
  int b = blockIdx.x >> 4, hh = blockIdx.x & 15;
  int tid = threadIdx.x;
  __shared__ float qwl[NE];
  __shared__ float w_[NTT];
  __shared__ float red[256];
  __shared__ int mask_is_i32;
  if (tid == 0) {
    // Scan first 128 words (= 512 bytes, in-bounds for both layouts).
    // uint8 all-bool data makes words like 0x01010101 (>1) -> uint8 layout.
    const unsigned int* w = (const unsigned int*)maskp;
    int i32 = 1;
    for (int i = 0; i < 128; ++i) { if (w[i] > 1u) { i32 = 0; break; } }
    mask_is_i32 = i32;
  }
  for (int i = tid; i < NE; i += 256) qwl[i] = qW[(size_t)(b * NH + hh) * NE + i];
  __syncthreads();
  int t = tid & 63, ec = tid >> 6;
  const float* xr = X + ((size_t)b * NTT + t) * NE + ec * 256;
  float part = 0.f;
#pragma unroll 4
  for (int i = 0; i < 256; i += 4) {
    float4 x4 = *reinterpret_cast<const float4*>(xr + i);
    part += qwl[ec * 256 + i] * x4.x + qwl[ec * 256 + i + 1] * x4.y +
            qwl[ec * 256 + i + 2] * x4.z + qwl[ec * 256 + i + 3] * x4.w;
  }
  red[ec * 64 + t] = part; __syncthreads();
  float sco = -INFINITY;
  if (tid < 64) {
    float s = (red[tid] + red[64 + tid] + red[128 + tid] + red[192 + tid]) * 0.125f;
    int idx = b * NTT + tid;
    bool valid = mask_is_i32 ? (((const int*)maskp)[idx] != 0)
                             : (((const unsigned char*)maskp)[idx] != 0);
    sco = valid ? s : -INFINITY;
  }
  __syncthreads();
  red[tid] = (tid < 64) ? sco : -INFINITY; __syncthreads();
  for (int o = 128; o; o >>= 1) { if (tid < o) red[tid] = fmaxf(red[tid], red[tid + o]); __syncthreads(); }
  float mx = red[0]; __syncthreads();
  float e = (tid < 64) ? __expf(sco - mx) : 0.f;
  red[tid] = e; __syncthreads();
  for (int o = 128; o; o >>= 1) { if (tid < o) red[tid] += red[tid + o]; __syncthreads(); }
  if (tid < 64) w_[tid] = e / red[0];
  __syncthreads();
  float a0 = 0.f, a1 = 0.f, a2 = 0.f, a3 = 0.f;
  for (int t2 = 0; t2 < NTT; ++t2) {
    float wt = w_[t2];
    const float* xr2 = X + ((size_t)b * NTT + t2) * NE;
    a0 += wt * xr2[tid]; a1 += wt * xr2[tid + 256]; a2 += wt * xr2[tid + 512]; a3 += wt * xr2[tid + 768];
  }
  float* o = wX + (size_t)(b * NH + hh) * NE;
  o[tid] = a0; o[tid + 256] = a1; o[tid + 512] = a2; o[tid + 768] = a3;
}

// ---------------- o_enc[b,h*64+d] += sum_e wX[b,h,e] Wv[e,h*64+d] ----------------
__global__ __launch_bounds__(256) void oenc_kernel(const float* __restrict__ wX,
    const float* __restrict__ Wv, float* __restrict__ o_enc) {
  int hh = blockIdx.x >> 2, ec = blockIdx.x & 3;
  int tid = threadIdx.x, d = tid & 63, es = tid >> 6;
  __shared__ float wl[8][256];
  __shared__ float red[4][64][8];
  for (int i = tid; i < 8 * 256; i += 256) {
    int r = i >> 8, e = i & 255;
    wl[r][e] = wX[(size_t)(r * NH + hh) * NE + ec * 256 + e];
  }
  __syncthreads();
  float acc[8] = {0.f, 0.f, 0.f, 0.f, 0.f, 0.f, 0.f, 0.f};
  for (int e = es * 64; e < es * 64 + 64; ++e) {
    float wv = Wv[(size_t)(ec * 256 + e) * NE + hh * 64 + d];
#pragma unroll
    for (int r = 0; r < 8; ++r) acc[r] += wl[r][e] * wv;
  }
#pragma unroll
  for (int r = 0; r < 8; ++r) red[es][d][r] = acc[r];
  __syncthreads();
  if (es == 0) {
#pragma unroll
    for (int r = 0; r < 8; ++r) {
      float v = red[0][d][r] + red[1][d][r] + red[2][d][r] + red[3][d][r];
      atomicAdd(&o_enc[(size_t)r * NE + hh * 64 + d], v);
    }
  }
}

// ---------------- g = gelu(a) * b ----------------
__global__ void gelu_mul_kernel(const float* __restrict__ a, const float* __restrict__ b,
                                float* __restrict__ g, int n) {
  int i = blockIdx.x * blockDim.x + threadIdx.x;
  if (i < n) { float x = a[i]; g[i] = 0.5f * x * (1.f + erff(x * 0.70710678118f)) * b[i]; }
}

// ---------------- write fresh k,v rows into output attention_state ----------------
__global__ void kv_out_kernel(const float* __restrict__ kv, float* __restrict__ out_ast,
                              const int* __restrict__ tixp) {
  int l = blockIdx.x >> 4, r = blockIdx.x & 15;
  int tix = tixp[0];
  const float* src = kv + (size_t)(l * 16 + r) * NE;
  float* dst = out_ast + (((size_t)(l * 16 + r)) * NIMG + tix) * NE;
  for (int i = threadIdx.x; i < NE; i += 256) dst[i] = src[i];
}

extern "C" void kernel_launch(void* const* d_in, const int* in_sizes, int n_in,
                              void* d_out, int out_size, void* d_ws, size_t ws_size,
                              hipStream_t stream) {
  const float* enc_state = (const float*)d_in[0];
  const float* ast_in    = (const float*)d_in[1];
  const void* amask      = d_in[2];
  const int* prev = (const int*)d_in[3];
  const int* tix  = (const int*)d_in[4];
  const float* embed_tok = (const float*)d_in[5];
  const float* embed_pos = (const float*)d_in[6];
  const float* lnemb_s = (const float*)d_in[7];
  const float* lnemb_b = (const float*)d_in[8];
  const float* psb = (const float*)d_in[9];
  const float* Wsq = (const float*)d_in[10];
  const float* Wsk = (const float*)d_in[11];
  const float* Wsv = (const float*)d_in[12];
  const float* Wso = (const float*)d_in[13];
  const float* sls = (const float*)d_in[14];
  const float* slb = (const float*)d_in[15];
  const float* peb = (const float*)d_in[16];
  const float* Weq = (const float*)d_in[17];
  const float* Wek = (const float*)d_in[18];
  const float* Wev = (const float*)d_in[19];
  const float* Weo = (const float*)d_in[20];
  const float* els = (const float*)d_in[21];
  const float* elb = (const float*)d_in[22];
  const float* g0b = (const float*)d_in[23];
  const float* Wf0 = (const float*)d_in[24];
  const float* Wf1 = (const float*)d_in[25];
  const float* g1b = (const float*)d_in[26];
  const float* Wf2 = (const float*)d_in[27];
  const float* flb = (const float*)d_in[28];
  const float* Wlm = (const float*)d_in[29];

  float* ws = (float*)d_ws;
  float* logits = (float*)d_out;
  float* out_ast = logits + (size_t)NB * NV;

  hipMemsetAsync(d_ws, 0, AEND * sizeof(float), stream);
  hipMemsetAsync(d_out, 0, (size_t)NB * NV * sizeof(float), stream);

  copy_ast<<<4096, 256, 0, stream>>>((const float4*)ast_in, (float4*)out_ast, NL * 16 * NIMG * NE / 4);
  embed_kernel<<<NB, 256, 0, stream>>>(embed_tok, embed_pos, prev, tix, lnemb_b, lnemb_s, ws + DX0);

  for (int l = 0; l < NL; ++l) {
    float* xl  = (l == 0) ? (ws + DX0) : (ws + AX + (size_t)(l - 1) * 8192);
    float* xn  = ws + AX + (size_t)l * 8192;
    float* kvl = ws + AKV + (size_t)l * 16384;
    float* qsl = ws + AQS + (size_t)l * 8192;
    float* ssl = ws + ASS + (size_t)l * 8192;
    float* qel = ws + AQE + (size_t)l * 8192;
    float* oel = ws + AOE + (size_t)l * 8192;
    float* sel = ws + ASE + (size_t)l * 8192;
    float* gal = ws + AGA + (size_t)l * 32768;
    float* gbl = ws + AGB + (size_t)l * 32768;
    size_t wE = (size_t)l * NE * NE;
    size_t wG = (size_t)l * NE * NG;

    {  // a: qkv projections (k,v -> kv rows; q -> q_self)
      MvP p{}; p.W0 = Wsk + wE; p.W1 = Wsv + wE; p.W2 = Wsq + wE;
      p.out0 = kvl; p.out1 = kvl + 8 * NE; p.out2 = qsl;
      p.xin = xl; p.lnb2 = psb + (size_t)l * NE; p.lns2 = nullptr;
      p.K = NE; p.N = NE; p.CB = 4; p.KS = 16; p.nmat = 3; p.mode = 1;
      mv_kernel<<<3 * 4 * 16, 256, 0, stream>>>(p);
    }
    self_attn_kernel<<<NB * NH, 256, 0, stream>>>(qsl, kvl, ast_in + (size_t)l * 16 * NIMG * NE, tix, ws + DAT);
    {  // c: @ so
      MvP p{}; p.W0 = Wso + wE; p.out0 = ssl; p.xin = ws + DAT;
      p.K = NE; p.N = NE; p.CB = 4; p.KS = 16; p.nmat = 1; p.mode = 0;
      mv_kernel<<<64, 256, 0, stream>>>(p);
    }
    {  // d: x2 = x + LN(s_self); h2 = LN(x2, peb); q_enc = h2 @ eq
      MvP p{}; p.W0 = Weq + wE; p.out0 = qel; p.xin = xl; p.sres = ssl;
      p.lnb1 = slb + (size_t)l * NE; p.lns1 = sls + (size_t)l * NE; p.lnb2 = peb + (size_t)l * NE;
      p.x2store = ws + DX2;
      p.K = NE; p.N = NE; p.CB = 4; p.KS = 16; p.nmat = 1; p.mode = 2;
      mv_kernel<<<64, 256, 0, stream>>>(p);
    }
    qw_kernel<<<64, 256, 0, stream>>>(qel, Wek + wE, ws + DQW);
    cross_attn_kernel<<<NB * NH, 256, 0, stream>>>(ws + DQW, enc_state, amask, ws + DWX);
    oenc_kernel<<<64, 256, 0, stream>>>(ws + DWX, Wev + wE, oel);
    {  // h: @ eo
      MvP p{}; p.W0 = Weo + wE; p.out0 = sel; p.xin = oel;
      p.K = NE; p.N = NE; p.CB = 4; p.KS = 16; p.nmat = 1; p.mode = 0;
      mv_kernel<<<64, 256, 0, stream>>>(p);
    }
    {  // i: x3 = x2 + LN(s_enc); h = LN(x3, g0b); gA=h@fc0, gB=h@fc1
      MvP p{}; p.W0 = Wf0 + wG; p.W1 = Wf1 + wG; p.out0 = gal; p.out1 = gbl;
      p.xin = ws + DX2; p.sres = sel;
      p.lnb1 = elb + (size_t)l * NE; p.lns1 = els + (size_t)l * NE; p.lnb2 = g0b + (size_t)l * NE;
      p.x2store = ws + DX3;
      p.K = NE; p.N = NG; p.CB = 16; p.KS = 4; p.nmat = 2; p.mode = 2;
      mv_kernel<<<2 * 16 * 4, 256, 0, stream>>>(p);
    }
    gelu_mul_kernel<<<128, 256, 0, stream>>>(gal, gbl, ws + DG, NB * NG);
    {  // k: h2 = LN(g, g1b); x_{l+1} = x3 + h2 @ fc2
      MvP p{}; p.W0 = Wf2 + (size_t)l * NG * NE; p.out0 = xn; p.xin = ws + DG;
      p.lnb2 = g1b + (size_t)l * NG; p.resid = ws + DX3;
      p.K = NG; p.N = NE; p.CB = 4; p.KS = 16; p.nmat = 1; p.mode = 3;
      mv_kernel<<<64, 256, 0, stream>>>(p);
    }
  }
  {  // final: logits = LN(x4, final_ln_b) @ lm_head
    MvP p{}; p.W0 = Wlm; p.out0 = logits; p.xin = ws + AX + 3 * 8192;
    p.lnb2 = flb; p.lns2 = nullptr;
    p.K = NE; p.N = NV; p.CB = 65; p.KS = 16; p.nmat = 1; p.mode = 1;
    mv_kernel<<<65 * 16, 256, 0, stream>>>(p);
  }
  kv_out_kernel<<<NL * 16, 256, 0, stream>>>(ws + AKV, out_ast, tix);
}